// Round 1
// baseline (1008.395 us; speedup 1.0000x reference)
//
#include <hip/hip_runtime.h>
#include <hip/hip_bf16.h>
#include <math.h>

typedef __bf16 bf16x8 __attribute__((ext_vector_type(8)));
typedef float  f32x4  __attribute__((ext_vector_type(4)));

#define MFMA16(a, b, c) __builtin_amdgcn_mfma_f32_16x16x32_bf16((a), (b), (c), 0, 0, 0)

static constexpr int    kB  = 16;
static constexpr int    kS  = 2048;
static constexpr int    kC  = 512;
static constexpr size_t kNE = (size_t)kB * kS * kC;  // 16777216

static __device__ __forceinline__ void split_bf16(float v, __bf16 &hi, __bf16 &lo) {
  hi = (__bf16)v;                 // RNE
  lo = (__bf16)(v - (float)hi);   // residual, ~2^-17 combined rel error
}

// Load 16 fp32 from src, split to bf16 hi/lo, store to LDS at element offset o.
static __device__ __forceinline__ void stage_split16(
    const float* __restrict__ src, __bf16* hi, __bf16* lo, int o) {
  float4 v0 = *(const float4*)(src + 0);
  float4 v1 = *(const float4*)(src + 4);
  float4 v2 = *(const float4*)(src + 8);
  float4 v3 = *(const float4*)(src + 12);
  float vv[16] = {v0.x, v0.y, v0.z, v0.w, v1.x, v1.y, v1.z, v1.w,
                  v2.x, v2.y, v2.z, v2.w, v3.x, v3.y, v3.z, v3.w};
  bf16x8 h0, h1, l0, l1;
#pragma unroll
  for (int i = 0; i < 8; ++i) {
    __bf16 a, b;
    split_bf16(vv[i], a, b);     h0[i] = a; l0[i] = b;
    split_bf16(vv[8 + i], a, b); h1[i] = a; l1[i] = b;
  }
  *(bf16x8*)&hi[o]     = h0;
  *(bf16x8*)&hi[o + 8] = h1;
  *(bf16x8*)&lo[o]     = l0;
  *(bf16x8*)&lo[o + 8] = l1;
}

// ---------------- K1a: t = tanh(x'), split to bf16 hi/lo ----------------
__global__ __launch_bounds__(256) void k_tanh_split(
    const float* __restrict__ xp, __bf16* __restrict__ th, __bf16* __restrict__ tl) {
  size_t i = ((size_t)blockIdx.x * 256 + threadIdx.x) * 8;
  float4 a = *(const float4*)(xp + i);
  float4 b = *(const float4*)(xp + i + 4);
  float v[8] = {a.x, a.y, a.z, a.w, b.x, b.y, b.z, b.w};
  bf16x8 h, l;
#pragma unroll
  for (int k = 0; k < 8; ++k) {
    float t = tanhf(v[k]);
    __bf16 hh, ll;
    split_bf16(t, hh, ll);
    h[k] = hh; l[k] = ll;
  }
  *(bf16x8*)(th + i) = h;
  *(bf16x8*)(tl + i) = l;
}

// ---------------- K1c: x (fp32 [b][t][c]) -> bf16 transposed [b][c][t] ----------------
__global__ __launch_bounds__(256) void k_transpose_x(
    const float* __restrict__ x, __bf16* __restrict__ xbt) {
  __shared__ float tile[64][65];
  int bid = blockIdx.x;              // 16 * 32 * 8 = 4096
  int b   = bid >> 8;
  int t0  = ((bid >> 3) & 31) * 64;
  int c0  = (bid & 7) * 64;
  int row = threadIdx.x >> 2;        // 0..63
  int seg = threadIdx.x & 3;         // 0..3 (16 elems each)
  const float* src = x + (size_t)(b * kS + t0 + row) * kC + c0 + seg * 16;
  float4 v0 = *(const float4*)(src + 0);
  float4 v1 = *(const float4*)(src + 4);
  float4 v2 = *(const float4*)(src + 8);
  float4 v3 = *(const float4*)(src + 12);
  float vv[16] = {v0.x, v0.y, v0.z, v0.w, v1.x, v1.y, v1.z, v1.w,
                  v2.x, v2.y, v2.z, v2.w, v3.x, v3.y, v3.z, v3.w};
#pragma unroll
  for (int i = 0; i < 16; ++i) tile[row][seg * 16 + i] = vv[i];
  __syncthreads();
  // out: row now indexes c, seg*16+i indexes t
  bf16x8 o0, o1;
#pragma unroll
  for (int i = 0; i < 8; ++i) o0[i] = (__bf16)tile[seg * 16 + i][row];
#pragma unroll
  for (int i = 0; i < 8; ++i) o1[i] = (__bf16)tile[seg * 16 + 8 + i][row];
  __bf16* dst = xbt + (size_t)(b * kC + c0 + row) * kS + t0 + seg * 16;
  *(bf16x8*)(dst)     = o0;
  *(bf16x8*)(dst + 8) = o1;
}

// ---------------- K1b: q = x' @ W^T + bias, fp32-accurate via split-bf16 3-MFMA ----------------
__global__ __launch_bounds__(256) void k_qgemm(
    const float* __restrict__ xp, const float* __restrict__ W,
    const float* __restrict__ bias, __bf16* __restrict__ qh, __bf16* __restrict__ ql) {
  __shared__ __align__(16) __bf16 lds[4 * 4608];
  __bf16* Ah = lds;             // [64][72]
  __bf16* Al = lds + 4608;
  __bf16* Bh = lds + 9216;      // [64][72]  (W rows d, cols c)
  __bf16* Bl = lds + 13824;

  int bid = blockIdx.x;         // 512 m-tiles * 8 n-tiles
  int n0  = (bid & 7) * 64;
  int m0  = (bid >> 3) * 64;

  int tid  = threadIdx.x;
  int lane = tid & 63;
  int wave = tid >> 6;
  int qd   = lane >> 4;
  int cl   = lane & 15;
  int row  = tid >> 2;
  int seg  = tid & 3;

  f32x4 acc[4] = {};

  for (int kc = 0; kc < 8; ++kc) {
    stage_split16(xp + (size_t)(m0 + row) * kC + kc * 64 + seg * 16, Ah, Al, row * 72 + seg * 16);
    stage_split16(W  + (size_t)(n0 + row) * kC + kc * 64 + seg * 16, Bh, Bl, row * 72 + seg * 16);
    __syncthreads();
#pragma unroll
    for (int ks = 0; ks < 2; ++ks) {
      int ka = ks * 32 + qd * 8;
      bf16x8 ah = *(const bf16x8*)&Ah[(wave * 16 + cl) * 72 + ka];
      bf16x8 al = *(const bf16x8*)&Al[(wave * 16 + cl) * 72 + ka];
#pragma unroll
      for (int j = 0; j < 4; ++j) {
        bf16x8 bh = *(const bf16x8*)&Bh[(j * 16 + cl) * 72 + ka];
        bf16x8 bl = *(const bf16x8*)&Bl[(j * 16 + cl) * 72 + ka];
        acc[j] = MFMA16(ah, bh, acc[j]);
        acc[j] = MFMA16(ah, bl, acc[j]);
        acc[j] = MFMA16(al, bh, acc[j]);
      }
    }
    __syncthreads();
  }
#pragma unroll
  for (int j = 0; j < 4; ++j) {
    int d = n0 + j * 16 + cl;
    float bv = bias[d];
#pragma unroll
    for (int r = 0; r < 4; ++r) {
      int m = m0 + wave * 16 + qd * 4 + r;
      float v = acc[j][r] + bv;
      __bf16 h, l;
      split_bf16(v, h, l);
      qh[(size_t)m * kC + d] = h;
      ql[(size_t)m * kC + d] = l;
    }
  }
}

// ---------------- K2: fused flash attention ----------------
// score = T(hi+lo) . Q(hi+lo)^T via 3 MFMAs (fp32-accurate logits);
// online softmax; O += P_bf16 . Xbt; out = tanh(O / l).
__global__ __launch_bounds__(256, 2) void k_attn(
    const __bf16* __restrict__ th, const __bf16* __restrict__ tl,
    const __bf16* __restrict__ qh, const __bf16* __restrict__ ql,
    const __bf16* __restrict__ xbt, float* __restrict__ out) {
  __shared__ __align__(16) __bf16 lds[27648];   // 55296 B
  __bf16* Ah = lds;             // [64][72]  tanh-hi chunk
  __bf16* Al = lds + 4608;      // [64][72]  tanh-lo chunk
  __bf16* Bh = lds + 9216;      // [128][72] q-hi chunk
  __bf16* Bl = lds + 18432;     // [128][72] q-lo chunk
  __bf16* P  = lds;             // [64][136] aliases A region (phase-disjoint)
  __bf16* Xt = lds + 9216;      // [64][136] aliases Bh region (phase-disjoint)

  int bid = blockIdx.x;                       // 512
  int b   = (bid & 7) | ((bid >> 8) << 3);    // XCD-swizzle: same batch -> same XCD slot
  int s0  = ((bid >> 3) & 31) * 64;

  int tid  = threadIdx.x;
  int lane = tid & 63;
  int wave = tid >> 6;
  int qd   = lane >> 4;
  int cl   = lane & 15;

  const float LOG2E = 1.4426950408889634f;

  float m_r[4], l_r[4];
  f32x4 O[8][4] = {};
#pragma unroll
  for (int r = 0; r < 4; ++r) { m_r[r] = -INFINITY; l_r[r] = 0.f; }

  const size_t rowbase = (size_t)b * kS;

  for (int tt = 0; tt < 16; ++tt) {
    int t0 = tt * 128;
    f32x4 Sacc[8] = {};
    // ----- score phase: S[64 x 128] = T . Q^T over K=512 -----
    for (int kc = 0; kc < 8; ++kc) {
      { // stage A: 64 rows x 64 k
        int arow = tid >> 2, aseg = tid & 3;
        size_t g = (rowbase + s0 + arow) * kC + kc * 64 + aseg * 16;
        int o = arow * 72 + aseg * 16;
        *(bf16x8*)&Ah[o]     = *(const bf16x8*)(th + g);
        *(bf16x8*)&Ah[o + 8] = *(const bf16x8*)(th + g + 8);
        *(bf16x8*)&Al[o]     = *(const bf16x8*)(tl + g);
        *(bf16x8*)&Al[o + 8] = *(const bf16x8*)(tl + g + 8);
      }
      { // stage B: 128 q-rows x 64 k
        int brow = tid >> 1, bseg = tid & 1;
        size_t g = (rowbase + t0 + brow) * kC + kc * 64 + bseg * 32;
        int o = brow * 72 + bseg * 32;
#pragma unroll
        for (int u = 0; u < 4; ++u)
          *(bf16x8*)&Bh[o + u * 8] = *(const bf16x8*)(qh + g + u * 8);
#pragma unroll
        for (int u = 0; u < 4; ++u)
          *(bf16x8*)&Bl[o + u * 8] = *(const bf16x8*)(ql + g + u * 8);
      }
      __syncthreads();
#pragma unroll
      for (int ks = 0; ks < 2; ++ks) {
        int ka = ks * 32 + qd * 8;
        bf16x8 ah = *(const bf16x8*)&Ah[(wave * 16 + cl) * 72 + ka];
        bf16x8 al = *(const bf16x8*)&Al[(wave * 16 + cl) * 72 + ka];
#pragma unroll
        for (int j = 0; j < 8; ++j) {
          bf16x8 bh = *(const bf16x8*)&Bh[(j * 16 + cl) * 72 + ka];
          bf16x8 bl = *(const bf16x8*)&Bl[(j * 16 + cl) * 72 + ka];
          Sacc[j] = MFMA16(ah, bh, Sacc[j]);
          Sacc[j] = MFMA16(ah, bl, Sacc[j]);
          Sacc[j] = MFMA16(al, bh, Sacc[j]);
        }
      }
      __syncthreads();
    }
    // ----- online softmax (rows live in quads: row = wave*16 + qd*4 + r) -----
    float rmax[4];
#pragma unroll
    for (int r = 0; r < 4; ++r) {
      float v = Sacc[0][r];
#pragma unroll
      for (int j = 1; j < 8; ++j) v = fmaxf(v, Sacc[j][r]);
      rmax[r] = v;
    }
#pragma unroll
    for (int mk = 1; mk < 16; mk <<= 1)
#pragma unroll
      for (int r = 0; r < 4; ++r)
        rmax[r] = fmaxf(rmax[r], __shfl_xor(rmax[r], mk, 64));
    float alpha[4], rsum[4];
#pragma unroll
    for (int r = 0; r < 4; ++r) {
      float mn = fmaxf(m_r[r], rmax[r]);
      alpha[r] = exp2f((m_r[r] - mn) * LOG2E);   // exp2(-inf)=0 on first tile
      m_r[r] = mn;
      rsum[r] = 0.f;
    }
#pragma unroll
    for (int j = 0; j < 8; ++j)
#pragma unroll
      for (int r = 0; r < 4; ++r) {
        float p = exp2f((Sacc[j][r] - m_r[r]) * LOG2E);
        Sacc[j][r] = p;
        rsum[r] += p;
      }
#pragma unroll
    for (int mk = 1; mk < 16; mk <<= 1)
#pragma unroll
      for (int r = 0; r < 4; ++r)
        rsum[r] += __shfl_xor(rsum[r], mk, 64);
    f32x4 av;
#pragma unroll
    for (int r = 0; r < 4; ++r) {
      l_r[r] = l_r[r] * alpha[r] + rsum[r];
      av[r] = alpha[r];
    }
#pragma unroll
    for (int nc = 0; nc < 8; ++nc)
#pragma unroll
      for (int nt = 0; nt < 4; ++nt)
        O[nc][nt] *= av;
    // write P (C-layout -> A-layout via LDS); A region is dead here
#pragma unroll
    for (int j = 0; j < 8; ++j)
#pragma unroll
      for (int r = 0; r < 4; ++r)
        P[(wave * 16 + qd * 4 + r) * 136 + j * 16 + cl] = (__bf16)Sacc[j][r];
    __syncthreads();
    // ----- PV phase: O[64 x 512] += P[64 x 128] . Xbt[128 x 512] -----
#pragma unroll
    for (int nc = 0; nc < 8; ++nc) {
      {
        int xrow = tid >> 2, xseg = tid & 3;   // xrow = c within chunk, xseg covers t
        size_t g = ((size_t)b * kC + nc * 64 + xrow) * kS + t0 + xseg * 32;
        int o = xrow * 136 + xseg * 32;
#pragma unroll
        for (int u = 0; u < 4; ++u)
          *(bf16x8*)&Xt[o + u * 8] = *(const bf16x8*)(xbt + g + u * 8);
      }
      __syncthreads();
#pragma unroll
      for (int ks = 0; ks < 4; ++ks) {
        int ka = ks * 32 + qd * 8;
        bf16x8 pa = *(const bf16x8*)&P[(wave * 16 + cl) * 136 + ka];
#pragma unroll
        for (int nt = 0; nt < 4; ++nt) {
          bf16x8 xb = *(const bf16x8*)&Xt[(nt * 16 + cl) * 136 + ka];
          O[nc][nt] = MFMA16(pa, xb, O[nc][nt]);
        }
      }
      __syncthreads();
    }
  }
  // ----- epilogue: out = tanh(O / l) -----
#pragma unroll
  for (int r = 0; r < 4; ++r) {
    float inv = __builtin_amdgcn_rcpf(l_r[r]);   // l >= 1 always
    size_t rowoff = (rowbase + s0 + wave * 16 + qd * 4 + r) * kC;
#pragma unroll
    for (int nc = 0; nc < 8; ++nc)
#pragma unroll
      for (int nt = 0; nt < 4; ++nt) {
        float v = O[nc][nt][r] * inv;
        float e = exp2f(2.f * LOG2E * v);        // e^{2v}; |v| <= ~6, no overflow
        out[rowoff + nc * 64 + nt * 16 + cl] = 1.f - 2.f * __builtin_amdgcn_rcpf(e + 1.f);
      }
  }
}

extern "C" void kernel_launch(void* const* d_in, const int* in_sizes, int n_in,
                              void* d_out, int out_size, void* d_ws, size_t ws_size,
                              hipStream_t stream) {
  const float* x    = (const float*)d_in[0];
  const float* xp   = (const float*)d_in[1];
  const float* W    = (const float*)d_in[2];
  const float* bias = (const float*)d_in[3];
  float* out = (float*)d_out;

  // workspace layout (bf16): t_hi | t_lo | q_hi | q_lo | x_bt  -> 5 * 16.78M * 2B = 160 MiB
  __bf16* ws  = (__bf16*)d_ws;
  __bf16* th  = ws;
  __bf16* tl  = ws + kNE;
  __bf16* qh  = ws + 2 * kNE;
  __bf16* ql  = ws + 3 * kNE;
  __bf16* xbt = ws + 4 * kNE;

  k_tanh_split<<<8192, 256, 0, stream>>>(xp, th, tl);
  k_transpose_x<<<4096, 256, 0, stream>>>(x, xbt);
  k_qgemm<<<4096, 256, 0, stream>>>(xp, W, bias, qh, ql);
  k_attn<<<512, 256, 0, stream>>>(th, tl, qh, ql, xbt, out);
}